// Round 7
// baseline (221.897 us; speedup 1.0000x reference)
//
#include <hip/hip_runtime.h>
#include <hip/hip_bf16.h>

#define DEV static __device__ __forceinline__

typedef __attribute__((ext_vector_type(8))) short bf16x8;
typedef __attribute__((ext_vector_type(4))) float f32x4;

DEV float sigm(float x) { return 1.0f / (1.0f + __expf(-x)); }

DEV unsigned pack2bf(float a, float b) {
    unsigned ua = __float_as_uint(a); ua = (ua + 0x7FFF + ((ua >> 16) & 1)) >> 16;
    unsigned ub = __float_as_uint(b); ub = (ub + 0x7FFF + ((ub >> 16) & 1)) >> 16;
    return ua | (ub << 16);
}
DEV unsigned short f2bf(float a) {
    unsigned ua = __float_as_uint(a);
    return (unsigned short)((ua + 0x7FFF + ((ua >> 16) & 1)) >> 16);
}
DEV float bfu2f(unsigned short u) { return __uint_as_float(((unsigned)u) << 16); }

// B=2, N=256, Nh=192, D=128, R=20

// Kernel A: main blocks (<512): s_all, x (stored bf16). block 536: Wft panel.
// blocks 512-535: v_bf copy.
__global__ __launch_bounds__(256) void kA(
    const float* __restrict__ s_heavy, const int* __restrict__ is_h,
    const float* __restrict__ h_emb, const float* __restrict__ norm1_w,
    const float* __restrict__ W_i1, const float* __restrict__ b_i1,
    const float* __restrict__ W_i2, const float* __restrict__ b_i2,
    const float* __restrict__ W_filter, const float* __restrict__ b_filter,
    const float* __restrict__ v_all,
    float* __restrict__ s_all, unsigned short* __restrict__ x_bf,
    unsigned short* __restrict__ v_bf, unsigned* __restrict__ Wftg)
{
    const int blk = blockIdx.x;
    const int t = threadIdx.x;
    if (blk >= 512) {
        if (blk == 536) {
            for (int e = t; e < 6144; e += 256) {
                int c = e >> 4, kk = e & 15;
                int r0 = 2 * kk, r1 = r0 + 1;
                float v0 = (r0 < 20) ? W_filter[r0 * 384 + c] : ((r0 == 20) ? b_filter[c] : 0.f);
                float v1 = (r1 < 20) ? W_filter[r1 * 384 + c] : 0.f;
                Wftg[c * 16 + kk] = pack2bf(v0, v1);
            }
        } else {
            const int base = (blk - 512) * 8192 + t;
            #pragma unroll
            for (int k = 0; k < 32; ++k) {
                int idx = base + k * 256;
                v_bf[idx] = f2bf(v_all[idx]);
            }
        }
        return;
    }
    const int bi = blk;
    const int b = bi >> 8, i = bi & 255;
    __shared__ float y[128];
    __shared__ float o[256];
    __shared__ float h[128];
    __shared__ float red[4];

    float s = 0.f;
    if (t < 128) {
        if (is_h[bi] != 0) s = h_emb[t];
        else if (i < 192) s = s_heavy[(b * 192 + i) * 128 + t];
        s_all[bi * 128 + t] = s;
    }
    float ss = s * s;
    #pragma unroll
    for (int off = 32; off > 0; off >>= 1) ss += __shfl_xor(ss, off, 64);
    if ((t & 63) == 0) red[t >> 6] = ss;
    __syncthreads();
    float v = (red[0] + red[1] + red[2] + red[3]) * (1.0f / 128.0f);
    float inv = rsqrtf(v + 1e-6f);
    if (t < 128) y[t] = s * inv * (1.0f + norm1_w[t]);
    __syncthreads();

    float acc = b_i1[t];
    #pragma unroll 8
    for (int k = 0; k < 128; ++k) acc += y[k] * W_i1[k * 256 + t];
    o[t] = acc;
    __syncthreads();
    if (t < 128) {
        float a = o[t], g = o[t + 128];
        h[t] = a * sigm(a) * sigm(g);
    }
    __syncthreads();
    for (int c = t; c < 384; c += 256) {
        float a2 = b_i2[c];
        #pragma unroll 8
        for (int k = 0; k < 128; ++k) a2 += h[k] * W_i2[k * 384 + c];
        x_bf[(long)bi * 384 + c] = f2bf(a2);
    }
}

// Kernel B3: 2048 blocks = 512 bi x 4 j-slices(64); 384 thr = 6 waves.
// phi[64x32] bf16 in LDS (rbf*mask | mask | pad); wave wv owns filter cols [64wv,64wv+64).
// Per nt: B-frag from global Wft panel, 4 MFMA (K=32) -> Wij frags; consume in-register:
//   waves 0-1: dq += Wij*x;  waves 2-3: dmuR[r3] += Wij*x*dir;  waves 4-5: dmumu[r3] += Wij*x*v.
// j-sum finished with 2 shfl_xor; partials to P[js][b][i][896] (kC2 layout).
__global__ __launch_bounds__(384) void kB3(
    const float* __restrict__ rbf, const float* __restrict__ dir_ij,
    const float* __restrict__ mask_ij,
    const unsigned short* __restrict__ x_bf, const unsigned short* __restrict__ v_bf,
    const unsigned* __restrict__ Wftg, float* __restrict__ P)
{
    const int blk = blockIdx.x;
    const int bi = blk >> 2, js = blk & 3;
    const int b = bi >> 8, i = bi & 255;
    const int j0 = js * 64;
    const int t = threadIdx.x, lane = t & 63, wv = t >> 6;
    const int g = lane >> 4, l16 = lane & 15;

    __shared__ unsigned phi[64 * 20];   // [j][kk<16], row stride 20 u32 (16B-aligned frags)
    __shared__ float dir_s[192];
    __shared__ float mask_s[64];

    if (t < 64) mask_s[t] = mask_ij[(long)bi * 256 + j0 + t];
    if (t >= 64 && t < 256) dir_s[t - 64] = dir_ij[(long)bi * 768 + j0 * 3 + (t - 64)];
    __syncthreads();

    const float* rbf_b = rbf + ((long)bi * 256 + j0) * 20;
    for (int e = t; e < 1024; e += 384) {
        int j = e >> 4, kk = e & 15;
        float m = mask_s[j];
        int r0 = 2 * kk;
        float v0 = 0.f, v1 = 0.f;
        if (r0 < 20) { v0 = rbf_b[j * 20 + r0] * m; v1 = (r0 + 1 < 20) ? rbf_b[j * 20 + r0 + 1] * m : 0.f; }
        else if (r0 == 20) v0 = m;
        phi[j * 20 + kk] = pack2bf(v0, v1);
    }
    __syncthreads();

    bf16x8 af[4];
    #pragma unroll
    for (int mt = 0; mt < 4; ++mt)
        af[mt] = *(const bf16x8*)&phi[(mt * 16 + l16) * 20 + g * 4];

    const int ctype = wv >> 1;              // 0: dq, 1: dmuR, 2: dmumu
    const long rowb = (long)b * 256 + j0;   // x/v row base
    float* Pb = P + (((long)js * 2 + b) * 256 + i) * 896;

    if (ctype == 0) {
        float accq[4] = {0.f, 0.f, 0.f, 0.f};
        #pragma unroll
        for (int nt = 0; nt < 4; ++nt) {
            const int c = wv * 64 + nt * 16 + l16;
            bf16x8 bfr = *(const bf16x8*)&Wftg[c * 16 + g * 4];
            f32x4 D[4];
            #pragma unroll
            for (int mt = 0; mt < 4; ++mt) {
                D[mt] = {0.f, 0.f, 0.f, 0.f};
                D[mt] = __builtin_amdgcn_mfma_f32_16x16x32_bf16(af[mt], bfr, D[mt], 0, 0, 0);
            }
            #pragma unroll
            for (int mt = 0; mt < 4; ++mt)
                #pragma unroll
                for (int e = 0; e < 4; ++e) {
                    int j = mt * 16 + g * 4 + e;
                    accq[nt] += D[mt][e] * bfu2f(x_bf[(rowb + j) * 384 + c]);
                }
        }
        #pragma unroll
        for (int nt = 0; nt < 4; ++nt) {
            float a = accq[nt];
            a += __shfl_xor(a, 16, 64); a += __shfl_xor(a, 32, 64);
            if (lane < 16) Pb[wv * 64 + nt * 16 + l16] = a;
        }
    } else if (ctype == 1) {
        float acc3[4][3];
        #pragma unroll
        for (int nt = 0; nt < 4; ++nt) { acc3[nt][0] = 0.f; acc3[nt][1] = 0.f; acc3[nt][2] = 0.f; }
        #pragma unroll
        for (int nt = 0; nt < 4; ++nt) {
            const int c = wv * 64 + nt * 16 + l16;     // 128..255
            bf16x8 bfr = *(const bf16x8*)&Wftg[c * 16 + g * 4];
            f32x4 D[4];
            #pragma unroll
            for (int mt = 0; mt < 4; ++mt) {
                D[mt] = {0.f, 0.f, 0.f, 0.f};
                D[mt] = __builtin_amdgcn_mfma_f32_16x16x32_bf16(af[mt], bfr, D[mt], 0, 0, 0);
            }
            #pragma unroll
            for (int mt = 0; mt < 4; ++mt)
                #pragma unroll
                for (int e = 0; e < 4; ++e) {
                    int j = mt * 16 + g * 4 + e;
                    float val = D[mt][e] * bfu2f(x_bf[(rowb + j) * 384 + c]);
                    #pragma unroll
                    for (int r3 = 0; r3 < 3; ++r3)
                        acc3[nt][r3] += val * dir_s[j * 3 + r3];
                }
        }
        #pragma unroll
        for (int nt = 0; nt < 4; ++nt)
            #pragma unroll
            for (int r3 = 0; r3 < 3; ++r3) {
                float a = acc3[nt][r3];
                a += __shfl_xor(a, 16, 64); a += __shfl_xor(a, 32, 64);
                if (lane < 16) Pb[128 + r3 * 128 + (wv - 2) * 64 + nt * 16 + l16] = a;
            }
    } else {
        float acc3[4][3];
        #pragma unroll
        for (int nt = 0; nt < 4; ++nt) { acc3[nt][0] = 0.f; acc3[nt][1] = 0.f; acc3[nt][2] = 0.f; }
        #pragma unroll
        for (int nt = 0; nt < 4; ++nt) {
            const int c = wv * 64 + nt * 16 + l16;     // 256..383
            const int d = c - 256;
            bf16x8 bfr = *(const bf16x8*)&Wftg[c * 16 + g * 4];
            f32x4 D[4];
            #pragma unroll
            for (int mt = 0; mt < 4; ++mt) {
                D[mt] = {0.f, 0.f, 0.f, 0.f};
                D[mt] = __builtin_amdgcn_mfma_f32_16x16x32_bf16(af[mt], bfr, D[mt], 0, 0, 0);
            }
            #pragma unroll
            for (int mt = 0; mt < 4; ++mt)
                #pragma unroll
                for (int e = 0; e < 4; ++e) {
                    int j = mt * 16 + g * 4 + e;
                    float val = D[mt][e] * bfu2f(x_bf[(rowb + j) * 384 + c]);
                    #pragma unroll
                    for (int r3 = 0; r3 < 3; ++r3)
                        acc3[nt][r3] += val * bfu2f(v_bf[(rowb + j) * 384 + r3 * 128 + d]);
                }
        }
        #pragma unroll
        for (int nt = 0; nt < 4; ++nt)
            #pragma unroll
            for (int r3 = 0; r3 < 3; ++r3) {
                float a = acc3[nt][r3];
                a += __shfl_xor(a, 16, 64); a += __shfl_xor(a, 32, 64);
                if (lane < 16) Pb[512 + r3 * 128 + (wv - 4) * 64 + nt * 16 + l16] = a;
            }
    }
}

// Kernel C2: paired mixing. Two rows per block (512 thr), sums the 4 j-slice partials.
__global__ __launch_bounds__(512) void kC2(
    const float* __restrict__ W_mu, const float* __restrict__ norm2_w,
    const float* __restrict__ W_m1, const float* __restrict__ b_m1,
    const float* __restrict__ W_m2, const float* __restrict__ b_m2,
    const float* __restrict__ s_all, const float* __restrict__ v_all,
    const float* __restrict__ P,
    float* __restrict__ q_out, float* __restrict__ mu_out)
{
    const int h = threadIdx.x >> 8, tt = threadIdx.x & 255;
    const int bi = blockIdx.x * 2 + h;
    const int b = bi >> 8, i = bi & 255;
    __shared__ float mu_s[2][384];
    __shared__ float muV[2][384], muW[2][384];
    __shared__ float ctxl[2][256];
    __shared__ float o[2][256];
    __shared__ float hh[2][128];
    __shared__ float x2s[2][384];
    __shared__ float red[2][4];

    const float* Pb0 = P + ((long)b * 256 + i) * 896;
    const long kst = (long)2 * 256 * 896;
    for (int idx = tt; idx < 384; idx += 256) {
        float dm = 0.f;
        #pragma unroll
        for (int ks = 0; ks < 4; ++ks)
            dm += Pb0[ks * kst + 128 + idx] + Pb0[ks * kst + 512 + idx];
        mu_s[h][idx] = v_all[(long)bi * 384 + idx] + dm;
    }
    float qv = 0.f;
    if (tt < 128) {
        float dq = 0.f;
        #pragma unroll
        for (int ks = 0; ks < 4; ++ks) dq += Pb0[ks * kst + tt];
        qv = s_all[bi * 128 + tt] + dq;
    }
    __syncthreads();

    float m0 = 0.f, m1 = 0.f, m2 = 0.f;
    #pragma unroll 8
    for (int k = 0; k < 128; ++k) {
        float ww = W_mu[k * 256 + tt];
        m0 += mu_s[h][k] * ww;
        m1 += mu_s[h][128 + k] * ww;
        m2 += mu_s[h][256 + k] * ww;
    }
    if (tt < 128) { muV[h][tt] = m0; muV[h][128 + tt] = m1; muV[h][256 + tt] = m2; }
    else { int d2 = tt - 128; muW[h][d2] = m0; muW[h][128 + d2] = m1; muW[h][256 + d2] = m2; }

    float ss = qv * qv;
    #pragma unroll
    for (int off = 32; off > 0; off >>= 1) ss += __shfl_xor(ss, off, 64);
    if ((tt & 63) == 0) red[h][tt >> 6] = ss;
    __syncthreads();
    float mean = (red[h][0] + red[h][1] + red[h][2] + red[h][3]) * (1.0f / 128.0f);
    if (tt < 128) {
        ctxl[h][tt] = qv * rsqrtf(mean + 1e-6f) * (1.0f + norm2_w[tt]);
    } else {
        int d2 = tt - 128;
        ctxl[h][tt] = sqrtf(muV[h][d2] * muV[h][d2] + muV[h][128 + d2] * muV[h][128 + d2]
                            + muV[h][256 + d2] * muV[h][256 + d2] + 1e-6f);
    }
    __syncthreads();

    float acc = b_m1[tt];
    #pragma unroll 8
    for (int k = 0; k < 256; ++k) acc += ctxl[h][k] * W_m1[k * 256 + tt];
    o[h][tt] = acc;
    __syncthreads();
    if (tt < 128) { float a = o[h][tt], gg = o[h][tt + 128]; hh[h][tt] = a * sigm(a) * sigm(gg); }
    __syncthreads();
    for (int c = tt; c < 384; c += 256) {
        float a2 = b_m2[c];
        #pragma unroll 8
        for (int k = 0; k < 128; ++k) a2 += hh[h][k] * W_m2[k * 384 + c];
        x2s[h][c] = a2;
    }
    __syncthreads();

    if (tt < 128) {
        const int d = tt;
        float vw = muV[h][d] * muW[h][d] + muV[h][128 + d] * muW[h][128 + d]
                 + muV[h][256 + d] * muW[h][256 + d];
        if (i < 192)
            q_out[((long)b * 192 + i) * 128 + d] = qv + x2s[h][d] + x2s[h][256 + d] * vw;
        #pragma unroll
        for (int r = 0; r < 3; ++r)
            mu_out[((long)bi * 3 + r) * 128 + d] =
                mu_s[h][r * 128 + d] + x2s[h][128 + d] * muW[h][r * 128 + d];
    }
}

extern "C" void kernel_launch(void* const* d_in, const int* in_sizes, int n_in,
                              void* d_out, int out_size, void* d_ws, size_t ws_size,
                              hipStream_t stream) {
    (void)in_sizes; (void)n_in; (void)out_size;
    const float* s_heavy  = (const float*)d_in[0];
    const float* v_all    = (const float*)d_in[1];
    const float* rbf      = (const float*)d_in[2];
    const float* dir_ij   = (const float*)d_in[3];
    const float* mask_ij  = (const float*)d_in[4];
    const int*   is_h     = (const int*)d_in[5];
    const float* h_emb    = (const float*)d_in[6];
    const float* W_filter = (const float*)d_in[7];
    const float* b_filter = (const float*)d_in[8];
    const float* norm1_w  = (const float*)d_in[9];
    const float* W_i1     = (const float*)d_in[10];
    const float* b_i1     = (const float*)d_in[11];
    const float* W_i2     = (const float*)d_in[12];
    const float* b_i2     = (const float*)d_in[13];
    const float* norm2_w  = (const float*)d_in[14];
    const float* W_m1     = (const float*)d_in[15];
    const float* b_m1     = (const float*)d_in[16];
    const float* W_m2     = (const float*)d_in[17];
    const float* b_m2     = (const float*)d_in[18];
    const float* W_mu     = (const float*)d_in[19];

    // ws layout (f32 units):
    //  s_all 0..65536 | x_bf(u16) 65536..163840 | v_bf(u16) 163840..262144
    //  Wftg(u32) 262144..268288 | P 268288..2103296
    const size_t need = (size_t)2103296 * 4;
    if (ws_size < need) return;
    float* ws    = (float*)d_ws;
    float* s_all = ws;
    unsigned short* x_bf = (unsigned short*)(ws + 65536);
    unsigned short* v_bf = (unsigned short*)(ws + 163840);
    unsigned* Wftg = (unsigned*)(ws + 262144);
    float* P     = ws + 268288;

    float* q_out  = (float*)d_out;               // (2,192,128)
    float* mu_out = q_out + 2 * 192 * 128;       // (2,256,3,128)

    kA<<<537, 256, 0, stream>>>(s_heavy, is_h, h_emb, norm1_w, W_i1, b_i1, W_i2, b_i2,
                                W_filter, b_filter, v_all, s_all, x_bf, v_bf, Wftg);
    kB3<<<2048, 384, 0, stream>>>(rbf, dir_ij, mask_ij, x_bf, v_bf, Wftg, P);
    kC2<<<256, 512, 0, stream>>>(W_mu, norm2_w, W_m1, b_m1, W_m2, b_m2,
                                 s_all, v_all, P, q_out, mu_out);
}

// Round 8
// 80.055 us; speedup vs baseline: 2.7718x; 2.7718x over previous
//
#include <hip/hip_runtime.h>
#include <hip/hip_bf16.h>

#define DEV static __device__ __forceinline__

typedef __attribute__((ext_vector_type(8))) short bf16x8;
typedef __attribute__((ext_vector_type(4))) float f32x4;

DEV float sigm(float x) { return 1.0f / (1.0f + __expf(-x)); }

DEV unsigned pack2bf(float a, float b) {
    unsigned ua = __float_as_uint(a); ua = (ua + 0x7FFF + ((ua >> 16) & 1)) >> 16;
    unsigned ub = __float_as_uint(b); ub = (ub + 0x7FFF + ((ub >> 16) & 1)) >> 16;
    return ua | (ub << 16);
}

// B=2, N=256, Nh=192, D=128, R=20

// Kernel A (paired, 2 rows/block): s_all; x = glu(rmsnorm(s_all)) @ W_i2 + b_i2 (f32)
__global__ __launch_bounds__(512) void kA(
    const float* __restrict__ s_heavy, const int* __restrict__ is_h,
    const float* __restrict__ h_emb, const float* __restrict__ norm1_w,
    const float* __restrict__ W_i1, const float* __restrict__ b_i1,
    const float* __restrict__ W_i2, const float* __restrict__ b_i2,
    float* __restrict__ s_all, float* __restrict__ x)
{
    const int h = threadIdx.x >> 8, tt = threadIdx.x & 255;
    const int bi = blockIdx.x * 2 + h;
    const int b = bi >> 8, i = bi & 255;
    __shared__ float y[2][128];
    __shared__ float o[2][256];
    __shared__ float hh[2][128];
    __shared__ float red[2][4];

    float s = 0.f;
    if (tt < 128) {
        if (is_h[bi] != 0) s = h_emb[tt];
        else if (i < 192) s = s_heavy[(b * 192 + i) * 128 + tt];
        s_all[bi * 128 + tt] = s;
    }
    float ss = s * s;
    #pragma unroll
    for (int off = 32; off > 0; off >>= 1) ss += __shfl_xor(ss, off, 64);
    if ((tt & 63) == 0) red[h][tt >> 6] = ss;
    __syncthreads();
    float v = (red[h][0] + red[h][1] + red[h][2] + red[h][3]) * (1.0f / 128.0f);
    float inv = rsqrtf(v + 1e-6f);
    if (tt < 128) y[h][tt] = s * inv * (1.0f + norm1_w[tt]);
    __syncthreads();

    float acc = b_i1[tt];
    #pragma unroll 8
    for (int k = 0; k < 128; ++k) acc += y[h][k] * W_i1[k * 256 + tt];
    o[h][tt] = acc;
    __syncthreads();
    if (tt < 128) {
        float a = o[h][tt], g = o[h][tt + 128];
        hh[h][tt] = a * sigm(a) * sigm(g);
    }
    __syncthreads();
    for (int c = tt; c < 384; c += 256) {
        float a2 = b_i2[c];
        #pragma unroll 8
        for (int k = 0; k < 128; ++k) a2 += hh[h][k] * W_i2[k * 384 + c];
        x[(long)bi * 384 + c] = a2;
    }
}

// Kernel X2: build frag-contiguous B panel.
// Bg uint4 per (b, kt, g, col): the 8 bf16 (j = kt*32+g*8 .. +7) a lane's MFMA B-frag needs.
// col<256: x[j,col]; col>=256: cg=col-256, r3=cg>>7, c3=cg&127: v[j,r3,c3]*x[j,256+c3].
// grid 64 = (b, kt, g); 640 threads = col.
__global__ __launch_bounds__(640) void kX2(
    const float* __restrict__ x, const float* __restrict__ v_all,
    unsigned* __restrict__ Bg)
{
    int blk = blockIdx.x;
    const int g = blk & 3; blk >>= 2;
    const int kt = blk & 7; const int b = blk >> 3;
    const int col = threadIdx.x;
    const int j0 = kt * 32 + g * 8;
    const float* xb = x + (long)b * 98304;
    const float* vb = v_all + (long)b * 98304;

    float vals[8];
    if (col < 256) {
        #pragma unroll
        for (int jj = 0; jj < 8; ++jj) vals[jj] = xb[(j0 + jj) * 384 + col];
    } else {
        const int cg = col - 256, r3 = cg >> 7, c3 = cg & 127;
        #pragma unroll
        for (int jj = 0; jj < 8; ++jj) {
            const int j = j0 + jj;
            vals[jj] = vb[j * 384 + r3 * 128 + c3] * xb[j * 384 + 256 + c3];
        }
    }
    uint4 outv = make_uint4(pack2bf(vals[0], vals[1]), pack2bf(vals[2], vals[3]),
                            pack2bf(vals[4], vals[5]), pack2bf(vals[6], vals[7]));
    *(uint4*)&Bg[(((long)(b * 8 + kt) * 4 + g) * 640 + col) * 4] = outv;
}

// Kernel B2f: per (b,i): A (96 x 256 bf16, LDS) @ Bg (640 x 256 bf16, frag-layout) via MFMA;
// in-register Wf contraction epilogue -> q, mu.  512 thr = 8 waves.
// A rows: 0-19 rbf*m, 20 m, 21-31 zero, 32+idx (idx=r3*21+r): rbf*m*dir (r=20 -> m*dir), 95 zero.
// B cols: 0-255 = x[:,0:256]; 256-639 = v[r3]*x2 (r3=(col-256)>>7).
// Wave w<2: T1 (rows 0-31, cols 0-127) -> dq.  w>=2: T3 (rows 0-31, cols 256-639) -> dmumu.
// All waves: T2 (rows 32-95, col 128+16w..) -> dmuR.
__global__ __launch_bounds__(512, 4) void kB2f(
    const float* __restrict__ rbf, const float* __restrict__ dir_ij,
    const float* __restrict__ mask_ij, const float* __restrict__ v_all,
    const float* __restrict__ W_filter, const float* __restrict__ b_filter,
    const float* __restrict__ s_all, const unsigned* __restrict__ Bg,
    float* __restrict__ q, float* __restrict__ mu)
{
    const int bi = blockIdx.x, b = bi >> 8;
    const int t = threadIdx.x;
    const int lane = t & 63, w = t >> 6, g = lane >> 4, l16 = lane & 15;

    __shared__ unsigned A_lds[96 * 132];   // 96 rows x 264 bf16 (k-pairs, pad)
    __shared__ float rbf_s[5120];
    __shared__ float dir_s[768];
    __shared__ float m_s[256];
    __shared__ float dmuR_s[384];
    __shared__ float dmumu_s[384];

    for (int i2 = t; i2 < 5120; i2 += 512) rbf_s[i2] = rbf[(long)bi * 5120 + i2];
    for (int i2 = t; i2 < 768; i2 += 512) dir_s[i2] = dir_ij[(long)bi * 768 + i2];
    for (int i2 = t; i2 < 256; i2 += 512) m_s[i2] = mask_ij[(long)bi * 256 + i2];
    __syncthreads();

    // ---- build A (bf16 pairs) ----
    for (int e = t; e < 96 * 128; e += 512) {
        int row = e >> 7, j2 = e & 127;
        float v01[2];
        #pragma unroll
        for (int u = 0; u < 2; ++u) {
            int j = 2 * j2 + u;
            float val = 0.f;
            if (row < 20) val = rbf_s[j * 20 + row] * m_s[j];
            else if (row == 20) val = m_s[j];
            else if (row >= 32) {
                int idx = row - 32;
                if (idx < 63) {
                    int r3 = (idx >= 42) ? 2 : ((idx >= 21) ? 1 : 0);
                    int r = idx - 21 * r3;
                    float base = (r < 20) ? rbf_s[j * 20 + r] : 1.f;
                    val = base * m_s[j] * dir_s[j * 3 + r3];
                }
            }
            v01[u] = val;
        }
        A_lds[row * 132 + j2] = pack2bf(v01[0], v01[1]);
    }
    __syncthreads();

    // ---- tile assignment (same as R5) ----
    int colR[4];
    #pragma unroll
    for (int ci = 0; ci < 4; ++ci) {
        int ct = (w < 2) ? (4 * w + ci) : (4 * w + 8 + ci);
        colR[ci] = ct * 16 + l16;
    }
    const int col2 = (8 + w) * 16 + l16;

    const unsigned* BgB = Bg + (long)b * 81920;   // 8*4*640*4

    f32x4 accR[4][2];
    f32x4 acc2[4];
    #pragma unroll
    for (int ci = 0; ci < 4; ++ci) {
        #pragma unroll
        for (int rt = 0; rt < 2; ++rt) accR[ci][rt] = {0.f, 0.f, 0.f, 0.f};
        acc2[ci] = {0.f, 0.f, 0.f, 0.f};
    }

    // ---- GEMM: K = 256 j = 8 k-steps of 32 ----
    #pragma unroll 2
    for (int kt = 0; kt < 8; ++kt) {
        bf16x8 af[6];
        #pragma unroll
        for (int rt = 0; rt < 6; ++rt)
            af[rt] = *(const bf16x8*)&A_lds[(rt * 16 + l16) * 132 + kt * 16 + g * 4];
        const unsigned* Bk = BgB + ((long)kt * 4 + g) * 640 * 4;
        bf16x8 bfr[5];
        #pragma unroll
        for (int u = 0; u < 4; ++u)
            bfr[u] = *(const bf16x8*)&Bk[colR[u] * 4];
        bfr[4] = *(const bf16x8*)&Bk[col2 * 4];
        #pragma unroll
        for (int ci = 0; ci < 4; ++ci) {
            accR[ci][0] = __builtin_amdgcn_mfma_f32_16x16x32_bf16(af[0], bfr[ci], accR[ci][0], 0, 0, 0);
            accR[ci][1] = __builtin_amdgcn_mfma_f32_16x16x32_bf16(af[1], bfr[ci], accR[ci][1], 0, 0, 0);
        }
        #pragma unroll
        for (int rt = 0; rt < 4; ++rt)
            acc2[rt] = __builtin_amdgcn_mfma_f32_16x16x32_bf16(af[2 + rt], bfr[4], acc2[rt], 0, 0, 0);
    }

    // ---- epilogue T2 -> dmuR ----
    {
        float p3[3] = {0.f, 0.f, 0.f};
        const int c = 128 + 16 * w + l16;
        #pragma unroll
        for (int rt = 0; rt < 4; ++rt) {
            #pragma unroll
            for (int e = 0; e < 4; ++e) {
                int l = rt * 16 + g * 4 + e;
                if (l < 63) {
                    int r3 = (l >= 42) ? 2 : ((l >= 21) ? 1 : 0);
                    int rr = l - 21 * r3;
                    float wgt = (rr < 20) ? W_filter[rr * 384 + c] : b_filter[c];
                    p3[r3] += wgt * acc2[rt][e];
                }
            }
        }
        #pragma unroll
        for (int r3 = 0; r3 < 3; ++r3) {
            float a = p3[r3];
            a += __shfl_xor(a, 16, 64);
            a += __shfl_xor(a, 32, 64);
            if (lane < 16) dmuR_s[r3 * 128 + 16 * w + l16] = a;
        }
    }

    // ---- epilogue T1/T3 -> dq / dmumu ----
    #pragma unroll
    for (int ci = 0; ci < 4; ++ci) {
        const int cwf = (w < 2) ? colR[ci] : (256 + ((colR[ci] - 256) & 127));
        float p = 0.f;
        #pragma unroll
        for (int rt = 0; rt < 2; ++rt) {
            #pragma unroll
            for (int e = 0; e < 4; ++e) {
                int row = rt * 16 + g * 4 + e;
                if (row <= 20) {
                    float wgt = (row < 20) ? W_filter[row * 384 + cwf] : b_filter[cwf];
                    p += wgt * accR[ci][rt][e];
                }
            }
        }
        p += __shfl_xor(p, 16, 64);
        p += __shfl_xor(p, 32, 64);
        if (lane < 16) {
            if (w < 2) {
                int c = colR[ci];
                q[bi * 128 + c] = s_all[bi * 128 + c] + p;
            } else {
                dmumu_s[colR[ci] - 256] = p;
            }
        }
    }
    __syncthreads();
    for (int e2 = t; e2 < 384; e2 += 512)
        mu[(long)bi * 384 + e2] = v_all[(long)bi * 384 + e2] + dmuR_s[e2] + dmumu_s[e2];
}

// Kernel C2: paired mixing (2 rows/block, 512 thr), reads q/mu.
__global__ __launch_bounds__(512) void kC2(
    const float* __restrict__ W_mu, const float* __restrict__ norm2_w,
    const float* __restrict__ W_m1, const float* __restrict__ b_m1,
    const float* __restrict__ W_m2, const float* __restrict__ b_m2,
    const float* __restrict__ q, const float* __restrict__ mu,
    float* __restrict__ q_out, float* __restrict__ mu_out)
{
    const int h = threadIdx.x >> 8, tt = threadIdx.x & 255;
    const int bi = blockIdx.x * 2 + h;
    const int b = bi >> 8, i = bi & 255;
    __shared__ float mu_s[2][384];
    __shared__ float muV[2][384], muW[2][384];
    __shared__ float ctxl[2][256];
    __shared__ float o[2][256];
    __shared__ float hh[2][128];
    __shared__ float x2s[2][384];
    __shared__ float red[2][4];

    for (int idx = tt; idx < 384; idx += 256) mu_s[h][idx] = mu[(long)bi * 384 + idx];
    float qv = 0.f;
    if (tt < 128) qv = q[bi * 128 + tt];
    __syncthreads();

    float m0 = 0.f, m1 = 0.f, m2 = 0.f;
    #pragma unroll 8
    for (int k = 0; k < 128; ++k) {
        float ww = W_mu[k * 256 + tt];
        m0 += mu_s[h][k] * ww;
        m1 += mu_s[h][128 + k] * ww;
        m2 += mu_s[h][256 + k] * ww;
    }
    if (tt < 128) { muV[h][tt] = m0; muV[h][128 + tt] = m1; muV[h][256 + tt] = m2; }
    else { int d2 = tt - 128; muW[h][d2] = m0; muW[h][128 + d2] = m1; muW[h][256 + d2] = m2; }

    float ss = qv * qv;
    #pragma unroll
    for (int off = 32; off > 0; off >>= 1) ss += __shfl_xor(ss, off, 64);
    if ((tt & 63) == 0) red[h][tt >> 6] = ss;
    __syncthreads();
    float mean = (red[h][0] + red[h][1] + red[h][2] + red[h][3]) * (1.0f / 128.0f);
    if (tt < 128) {
        ctxl[h][tt] = qv * rsqrtf(mean + 1e-6f) * (1.0f + norm2_w[tt]);
    } else {
        int d2 = tt - 128;
        ctxl[h][tt] = sqrtf(muV[h][d2] * muV[h][d2] + muV[h][128 + d2] * muV[h][128 + d2]
                            + muV[h][256 + d2] * muV[h][256 + d2] + 1e-6f);
    }
    __syncthreads();

    float acc = b_m1[tt];
    #pragma unroll 8
    for (int k = 0; k < 256; ++k) acc += ctxl[h][k] * W_m1[k * 256 + tt];
    o[h][tt] = acc;
    __syncthreads();
    if (tt < 128) { float a = o[h][tt], gg = o[h][tt + 128]; hh[h][tt] = a * sigm(a) * sigm(gg); }
    __syncthreads();
    for (int c = tt; c < 384; c += 256) {
        float a2 = b_m2[c];
        #pragma unroll 8
        for (int k = 0; k < 128; ++k) a2 += hh[h][k] * W_m2[k * 384 + c];
        x2s[h][c] = a2;
    }
    __syncthreads();

    if (tt < 128) {
        const int d = tt;
        float vw = muV[h][d] * muW[h][d] + muV[h][128 + d] * muW[h][128 + d]
                 + muV[h][256 + d] * muW[h][256 + d];
        if (i < 192)
            q_out[((long)b * 192 + i) * 128 + d] = qv + x2s[h][d] + x2s[h][256 + d] * vw;
        #pragma unroll
        for (int r = 0; r < 3; ++r)
            mu_out[((long)bi * 3 + r) * 128 + d] =
                mu_s[h][r * 128 + d] + x2s[h][128 + d] * muW[h][r * 128 + d];
    }
}

extern "C" void kernel_launch(void* const* d_in, const int* in_sizes, int n_in,
                              void* d_out, int out_size, void* d_ws, size_t ws_size,
                              hipStream_t stream) {
    (void)in_sizes; (void)n_in; (void)out_size;
    const float* s_heavy  = (const float*)d_in[0];
    const float* v_all    = (const float*)d_in[1];
    const float* rbf      = (const float*)d_in[2];
    const float* dir_ij   = (const float*)d_in[3];
    const float* mask_ij  = (const float*)d_in[4];
    const int*   is_h     = (const int*)d_in[5];
    const float* h_emb    = (const float*)d_in[6];
    const float* W_filter = (const float*)d_in[7];
    const float* b_filter = (const float*)d_in[8];
    const float* norm1_w  = (const float*)d_in[9];
    const float* W_i1     = (const float*)d_in[10];
    const float* b_i1     = (const float*)d_in[11];
    const float* W_i2     = (const float*)d_in[12];
    const float* b_i2     = (const float*)d_in[13];
    const float* norm2_w  = (const float*)d_in[14];
    const float* W_m1     = (const float*)d_in[15];
    const float* b_m1     = (const float*)d_in[16];
    const float* W_m2     = (const float*)d_in[17];
    const float* b_m2     = (const float*)d_in[18];
    const float* W_mu     = (const float*)d_in[19];

    // ws layout (f32 units): s_all 0 | x 65536 | q 262144 | mu 327680 | Bg(u32) 524288
    const size_t need = (size_t)(524288 + 163840) * 4;
    if (ws_size < need) return;
    float* ws    = (float*)d_ws;
    float* s_all = ws;
    float* x     = ws + 65536;
    float* q     = ws + 262144;
    float* mu    = ws + 327680;
    unsigned* Bg = (unsigned*)(ws + 524288);   // 2*8*4*640*4 u32 = 163840

    float* q_out  = (float*)d_out;               // (2,192,128)
    float* mu_out = q_out + 2 * 192 * 128;       // (2,256,3,128)

    kA<<<256, 512, 0, stream>>>(s_heavy, is_h, h_emb, norm1_w, W_i1, b_i1, W_i2, b_i2,
                                s_all, x);
    kX2<<<64, 640, 0, stream>>>(x, v_all, Bg);
    kB2f<<<512, 512, 0, stream>>>(rbf, dir_ij, mask_ij, v_all, W_filter, b_filter,
                                  s_all, Bg, q, mu);
    kC2<<<256, 512, 0, stream>>>(W_mu, norm2_w, W_m1, b_m1, W_m2, b_m2,
                                 q, mu, q_out, mu_out);
}

// Round 9
// 68.528 us; speedup vs baseline: 3.2381x; 1.1682x over previous
//
#include <hip/hip_runtime.h>
#include <hip/hip_bf16.h>

#define DEV static __device__ __forceinline__

typedef __attribute__((ext_vector_type(8))) short bf16x8;
typedef __attribute__((ext_vector_type(4))) float f32x4;

DEV float sigm(float x) { return 1.0f / (1.0f + __expf(-x)); }

DEV unsigned pack2bf(float a, float b) {
    unsigned ua = __float_as_uint(a); ua = (ua + 0x7FFF + ((ua >> 16) & 1)) >> 16;
    unsigned ub = __float_as_uint(b); ub = (ub + 0x7FFF + ((ub >> 16) & 1)) >> 16;
    return ua | (ub << 16);
}

// B=2, N=256, Nh=192, D=128, R=20

// Kernel A: one row per block (512 x 256): s_all; x = glu(rmsnorm(s_all)) @ W_i2 + b_i2
__global__ __launch_bounds__(256) void kA(
    const float* __restrict__ s_heavy, const int* __restrict__ is_h,
    const float* __restrict__ h_emb, const float* __restrict__ norm1_w,
    const float* __restrict__ W_i1, const float* __restrict__ b_i1,
    const float* __restrict__ W_i2, const float* __restrict__ b_i2,
    float* __restrict__ s_all, float* __restrict__ x)
{
    const int bi = blockIdx.x;
    const int b = bi >> 8, i = bi & 255;
    const int t = threadIdx.x;
    __shared__ float y[128];
    __shared__ float o[256];
    __shared__ float h[128];
    __shared__ float red[4];

    float s = 0.f;
    if (t < 128) {
        if (is_h[bi] != 0) s = h_emb[t];
        else if (i < 192) s = s_heavy[(b * 192 + i) * 128 + t];
        s_all[bi * 128 + t] = s;
    }
    float ss = s * s;
    #pragma unroll
    for (int off = 32; off > 0; off >>= 1) ss += __shfl_xor(ss, off, 64);
    if ((t & 63) == 0) red[t >> 6] = ss;
    __syncthreads();
    float v = (red[0] + red[1] + red[2] + red[3]) * (1.0f / 128.0f);
    float inv = rsqrtf(v + 1e-6f);
    if (t < 128) y[t] = s * inv * (1.0f + norm1_w[t]);
    __syncthreads();

    float acc = b_i1[t];
    #pragma unroll 8
    for (int k = 0; k < 128; ++k) acc += y[k] * W_i1[k * 256 + t];
    o[t] = acc;
    __syncthreads();
    if (t < 128) {
        float a = o[t], g = o[t + 128];
        h[t] = a * sigm(a) * sigm(g);
    }
    __syncthreads();
    for (int c = t; c < 384; c += 256) {
        float a2 = b_i2[c];
        #pragma unroll 8
        for (int k = 0; k < 128; ++k) a2 += h[k] * W_i2[k * 384 + c];
        x[(long)bi * 384 + c] = a2;
    }
}

// Kernel X2: build frag-contiguous B panel.
// Bg uint4 per (b, kt, g, col): the 8 bf16 (j = kt*32+g*8 .. +7) a lane's MFMA B-frag needs.
// col<256: x[j,col]; col>=256: cg=col-256, r3=cg>>7, c3=cg&127: v[j,r3,c3]*x[j,256+c3].
// grid 64 = (b, kt, g); 640 threads = col.
__global__ __launch_bounds__(640) void kX2(
    const float* __restrict__ x, const float* __restrict__ v_all,
    unsigned* __restrict__ Bg)
{
    int blk = blockIdx.x;
    const int g = blk & 3; blk >>= 2;
    const int kt = blk & 7; const int b = blk >> 3;
    const int col = threadIdx.x;
    const int j0 = kt * 32 + g * 8;
    const float* xb = x + (long)b * 98304;
    const float* vb = v_all + (long)b * 98304;

    float vals[8];
    if (col < 256) {
        #pragma unroll
        for (int jj = 0; jj < 8; ++jj) vals[jj] = xb[(j0 + jj) * 384 + col];
    } else {
        const int cg = col - 256, r3 = cg >> 7, c3 = cg & 127;
        #pragma unroll
        for (int jj = 0; jj < 8; ++jj) {
            const int j = j0 + jj;
            vals[jj] = vb[j * 384 + r3 * 128 + c3] * xb[j * 384 + 256 + c3];
        }
    }
    uint4 outv = make_uint4(pack2bf(vals[0], vals[1]), pack2bf(vals[2], vals[3]),
                            pack2bf(vals[4], vals[5]), pack2bf(vals[6], vals[7]));
    *(uint4*)&Bg[(((long)(b * 8 + kt) * 4 + g) * 640 + col) * 4] = outv;
}

// Kernel B2f: per (b,i): A (96 x 256 bf16, LDS) @ Bg (640 x 256 bf16, frag-layout) via MFMA;
// in-register Wf contraction epilogue -> q, mu.  512 thr = 8 waves.
__global__ __launch_bounds__(512, 4) void kB2f(
    const float* __restrict__ rbf, const float* __restrict__ dir_ij,
    const float* __restrict__ mask_ij, const float* __restrict__ v_all,
    const float* __restrict__ W_filter, const float* __restrict__ b_filter,
    const float* __restrict__ s_all, const unsigned* __restrict__ Bg,
    float* __restrict__ q, float* __restrict__ mu)
{
    const int bi = blockIdx.x, b = bi >> 8;
    const int t = threadIdx.x;
    const int lane = t & 63, w = t >> 6, g = lane >> 4, l16 = lane & 15;

    __shared__ unsigned A_lds[96 * 132];   // 96 rows x 264 bf16 (k-pairs, pad)
    __shared__ float rbf_s[5120];
    __shared__ float dir_s[768];
    __shared__ float m_s[256];
    __shared__ float dmuR_s[384];
    __shared__ float dmumu_s[384];

    for (int i2 = t; i2 < 5120; i2 += 512) rbf_s[i2] = rbf[(long)bi * 5120 + i2];
    for (int i2 = t; i2 < 768; i2 += 512) dir_s[i2] = dir_ij[(long)bi * 768 + i2];
    for (int i2 = t; i2 < 256; i2 += 512) m_s[i2] = mask_ij[(long)bi * 256 + i2];
    __syncthreads();

    // ---- build A (bf16 pairs) ----
    for (int e = t; e < 96 * 128; e += 512) {
        int row = e >> 7, j2 = e & 127;
        float v01[2];
        #pragma unroll
        for (int u = 0; u < 2; ++u) {
            int j = 2 * j2 + u;
            float val = 0.f;
            if (row < 20) val = rbf_s[j * 20 + row] * m_s[j];
            else if (row == 20) val = m_s[j];
            else if (row >= 32) {
                int idx = row - 32;
                if (idx < 63) {
                    int r3 = (idx >= 42) ? 2 : ((idx >= 21) ? 1 : 0);
                    int r = idx - 21 * r3;
                    float base = (r < 20) ? rbf_s[j * 20 + r] : 1.f;
                    val = base * m_s[j] * dir_s[j * 3 + r3];
                }
            }
            v01[u] = val;
        }
        A_lds[row * 132 + j2] = pack2bf(v01[0], v01[1]);
    }
    __syncthreads();

    // ---- tile assignment ----
    int colR[4];
    #pragma unroll
    for (int ci = 0; ci < 4; ++ci) {
        int ct = (w < 2) ? (4 * w + ci) : (4 * w + 8 + ci);
        colR[ci] = ct * 16 + l16;
    }
    const int col2 = (8 + w) * 16 + l16;

    const unsigned* BgB = Bg + (long)b * 81920;   // 8*4*640*4

    f32x4 accR[4][2];
    f32x4 acc2[4];
    #pragma unroll
    for (int ci = 0; ci < 4; ++ci) {
        #pragma unroll
        for (int rt = 0; rt < 2; ++rt) accR[ci][rt] = {0.f, 0.f, 0.f, 0.f};
        acc2[ci] = {0.f, 0.f, 0.f, 0.f};
    }

    // ---- GEMM: K = 256 j = 8 k-steps of 32 ----
    #pragma unroll 2
    for (int kt = 0; kt < 8; ++kt) {
        bf16x8 af[6];
        #pragma unroll
        for (int rt = 0; rt < 6; ++rt)
            af[rt] = *(const bf16x8*)&A_lds[(rt * 16 + l16) * 132 + kt * 16 + g * 4];
        const unsigned* Bk = BgB + ((long)kt * 4 + g) * 640 * 4;
        bf16x8 bfr[5];
        #pragma unroll
        for (int u = 0; u < 4; ++u)
            bfr[u] = *(const bf16x8*)&Bk[colR[u] * 4];
        bfr[4] = *(const bf16x8*)&Bk[col2 * 4];
        #pragma unroll
        for (int ci = 0; ci < 4; ++ci) {
            accR[ci][0] = __builtin_amdgcn_mfma_f32_16x16x32_bf16(af[0], bfr[ci], accR[ci][0], 0, 0, 0);
            accR[ci][1] = __builtin_amdgcn_mfma_f32_16x16x32_bf16(af[1], bfr[ci], accR[ci][1], 0, 0, 0);
        }
        #pragma unroll
        for (int rt = 0; rt < 4; ++rt)
            acc2[rt] = __builtin_amdgcn_mfma_f32_16x16x32_bf16(af[2 + rt], bfr[4], acc2[rt], 0, 0, 0);
    }

    // ---- epilogue T2 -> dmuR ----
    {
        float p3[3] = {0.f, 0.f, 0.f};
        const int c = 128 + 16 * w + l16;
        #pragma unroll
        for (int rt = 0; rt < 4; ++rt) {
            #pragma unroll
            for (int e = 0; e < 4; ++e) {
                int l = rt * 16 + g * 4 + e;
                if (l < 63) {
                    int r3 = (l >= 42) ? 2 : ((l >= 21) ? 1 : 0);
                    int rr = l - 21 * r3;
                    float wgt = (rr < 20) ? W_filter[rr * 384 + c] : b_filter[c];
                    p3[r3] += wgt * acc2[rt][e];
                }
            }
        }
        #pragma unroll
        for (int r3 = 0; r3 < 3; ++r3) {
            float a = p3[r3];
            a += __shfl_xor(a, 16, 64);
            a += __shfl_xor(a, 32, 64);
            if (lane < 16) dmuR_s[r3 * 128 + 16 * w + l16] = a;
        }
    }

    // ---- epilogue T1/T3 -> dq / dmumu ----
    #pragma unroll
    for (int ci = 0; ci < 4; ++ci) {
        const int cwf = (w < 2) ? colR[ci] : (256 + ((colR[ci] - 256) & 127));
        float p = 0.f;
        #pragma unroll
        for (int rt = 0; rt < 2; ++rt) {
            #pragma unroll
            for (int e = 0; e < 4; ++e) {
                int row = rt * 16 + g * 4 + e;
                if (row <= 20) {
                    float wgt = (row < 20) ? W_filter[row * 384 + cwf] : b_filter[cwf];
                    p += wgt * accR[ci][rt][e];
                }
            }
        }
        p += __shfl_xor(p, 16, 64);
        p += __shfl_xor(p, 32, 64);
        if (lane < 16) {
            if (w < 2) {
                int c = colR[ci];
                q[bi * 128 + c] = s_all[bi * 128 + c] + p;
            } else {
                dmumu_s[colR[ci] - 256] = p;
            }
        }
    }
    __syncthreads();
    for (int e2 = t; e2 < 384; e2 += 512)
        mu[(long)bi * 384 + e2] = v_all[(long)bi * 384 + e2] + dmuR_s[e2] + dmumu_s[e2];
}

// Kernel C3: one row per block, 512 blocks x 512 thr; split-K halves on the big loops.
__global__ __launch_bounds__(512) void kC3(
    const float* __restrict__ W_mu, const float* __restrict__ norm2_w,
    const float* __restrict__ W_m1, const float* __restrict__ b_m1,
    const float* __restrict__ W_m2, const float* __restrict__ b_m2,
    const float* __restrict__ q, const float* __restrict__ mu,
    float* __restrict__ q_out, float* __restrict__ mu_out)
{
    const int bi = blockIdx.x;
    const int b = bi >> 8, i = bi & 255;
    const int tt = threadIdx.x;          // 0..511
    const int c = tt & 255, kh = tt >> 8;
    __shared__ float mu_s[384];
    __shared__ float part[2][768];       // [khalf][r3*256+c]
    __shared__ float muV[384], muW[384];
    __shared__ float ctx[256];
    __shared__ float o_part[2][256];
    __shared__ float h[128];
    __shared__ float x2s[384];
    __shared__ float red[8];

    for (int idx = tt; idx < 384; idx += 512) mu_s[idx] = mu[(long)bi * 384 + idx];
    float qv = 0.f;
    if (tt < 128) qv = q[bi * 128 + tt];
    __syncthreads();

    // mu_mix (split-K: kh handles k in [64kh, 64kh+64))
    {
        float m0 = 0.f, m1 = 0.f, m2 = 0.f;
        const int k0 = kh * 64;
        #pragma unroll 8
        for (int k = k0; k < k0 + 64; ++k) {
            float ww = W_mu[k * 256 + c];
            m0 += mu_s[k] * ww;
            m1 += mu_s[128 + k] * ww;
            m2 += mu_s[256 + k] * ww;
        }
        part[kh][c] = m0; part[kh][256 + c] = m1; part[kh][512 + c] = m2;
    }
    // rmsnorm reduce (all waves; only waves 0-1 carry signal)
    float ss = qv * qv;
    #pragma unroll
    for (int off = 32; off > 0; off >>= 1) ss += __shfl_xor(ss, off, 64);
    if ((tt & 63) == 0) red[tt >> 6] = ss;
    __syncthreads();
    for (int idx = tt; idx < 768; idx += 512) {
        const int r3 = idx >> 8, cc = idx & 255;
        float val = part[0][idx] + part[1][idx];
        if (cc < 128) muV[r3 * 128 + cc] = val;
        else          muW[r3 * 128 + (cc - 128)] = val;
    }
    __syncthreads();
    float mean = (red[0] + red[1] + red[2] + red[3] + red[4] + red[5] + red[6] + red[7])
                 * (1.0f / 128.0f);
    if (tt < 128) {
        ctx[tt] = qv * rsqrtf(mean + 1e-6f) * (1.0f + norm2_w[tt]);
    } else if (tt < 256) {
        int d2 = tt - 128;
        ctx[tt] = sqrtf(muV[d2] * muV[d2] + muV[128 + d2] * muV[128 + d2]
                        + muV[256 + d2] * muV[256 + d2] + 1e-6f);
    }
    __syncthreads();

    // o = ctx @ W_m1 (split-K: kh handles k in [128kh, 128kh+128))
    {
        float acc = 0.f;
        const int k0 = kh * 128;
        #pragma unroll 8
        for (int k = k0; k < k0 + 128; ++k) acc += ctx[k] * W_m1[k * 256 + c];
        o_part[kh][c] = acc;
    }
    __syncthreads();
    if (tt < 128) {
        float a  = o_part[0][tt] + o_part[1][tt] + b_m1[tt];
        float gg = o_part[0][tt + 128] + o_part[1][tt + 128] + b_m1[tt + 128];
        h[tt] = a * sigm(a) * sigm(gg);
    }
    __syncthreads();
    // x2 = h @ W_m2 + b_m2 (384 cols, full K=128 per thread)
    if (tt < 384) {
        float a2 = b_m2[tt];
        #pragma unroll 8
        for (int k = 0; k < 128; ++k) a2 += h[k] * W_m2[k * 384 + tt];
        x2s[tt] = a2;
    }
    __syncthreads();

    if (tt < 128) {
        const int d = tt;
        float vw = muV[d] * muW[d] + muV[128 + d] * muW[128 + d] + muV[256 + d] * muW[256 + d];
        if (i < 192)
            q_out[((long)b * 192 + i) * 128 + d] = qv + x2s[d] + x2s[256 + d] * vw;
        #pragma unroll
        for (int r = 0; r < 3; ++r)
            mu_out[((long)bi * 3 + r) * 128 + d] =
                mu_s[r * 128 + d] + x2s[128 + d] * muW[r * 128 + d];
    }
}

extern "C" void kernel_launch(void* const* d_in, const int* in_sizes, int n_in,
                              void* d_out, int out_size, void* d_ws, size_t ws_size,
                              hipStream_t stream) {
    (void)in_sizes; (void)n_in; (void)out_size;
    const float* s_heavy  = (const float*)d_in[0];
    const float* v_all    = (const float*)d_in[1];
    const float* rbf      = (const float*)d_in[2];
    const float* dir_ij   = (const float*)d_in[3];
    const float* mask_ij  = (const float*)d_in[4];
    const int*   is_h     = (const int*)d_in[5];
    const float* h_emb    = (const float*)d_in[6];
    const float* W_filter = (const float*)d_in[7];
    const float* b_filter = (const float*)d_in[8];
    const float* norm1_w  = (const float*)d_in[9];
    const float* W_i1     = (const float*)d_in[10];
    const float* b_i1     = (const float*)d_in[11];
    const float* W_i2     = (const float*)d_in[12];
    const float* b_i2     = (const float*)d_in[13];
    const float* norm2_w  = (const float*)d_in[14];
    const float* W_m1     = (const float*)d_in[15];
    const float* b_m1     = (const float*)d_in[16];
    const float* W_m2     = (const float*)d_in[17];
    const float* b_m2     = (const float*)d_in[18];
    const float* W_mu     = (const float*)d_in[19];

    // ws layout (f32 units): s_all 0 | x 65536 | q 262144 | mu 327680 | Bg(u32) 524288
    const size_t need = (size_t)(524288 + 163840) * 4;
    if (ws_size < need) return;
    float* ws    = (float*)d_ws;
    float* s_all = ws;
    float* x     = ws + 65536;
    float* q     = ws + 262144;
    float* mu    = ws + 327680;
    unsigned* Bg = (unsigned*)(ws + 524288);   // 2*8*4*640*4 u32 = 163840

    float* q_out  = (float*)d_out;               // (2,192,128)
    float* mu_out = q_out + 2 * 192 * 128;       // (2,256,3,128)

    kA<<<512, 256, 0, stream>>>(s_heavy, is_h, h_emb, norm1_w, W_i1, b_i1, W_i2, b_i2,
                                s_all, x);
    kX2<<<64, 640, 0, stream>>>(x, v_all, Bg);
    kB2f<<<512, 512, 0, stream>>>(rbf, dir_ij, mask_ij, v_all, W_filter, b_filter,
                                  s_all, Bg, q, mu);
    kC3<<<512, 512, 0, stream>>>(W_mu, norm2_w, W_m1, b_m1, W_m2, b_m2,
                                 q, mu, q_out, mu_out);
}

// Round 10
// 63.722 us; speedup vs baseline: 3.4823x; 1.0754x over previous
//
#include <hip/hip_runtime.h>
#include <hip/hip_bf16.h>

#define DEV static __device__ __forceinline__

typedef __attribute__((ext_vector_type(8))) short bf16x8;
typedef __attribute__((ext_vector_type(4))) float f32x4;

DEV float sigm(float x) { return 1.0f / (1.0f + __expf(-x)); }

DEV unsigned pack2bf(float a, float b) {
    unsigned ua = __float_as_uint(a); ua = (ua + 0x7FFF + ((ua >> 16) & 1)) >> 16;
    unsigned ub = __float_as_uint(b); ub = (ub + 0x7FFF + ((ub >> 16) & 1)) >> 16;
    return ua | (ub << 16);
}

// B=2, N=256, Nh=192, D=128, R=20

// Kernel A: one row per block (512 x 256): s_all; x = glu(rmsnorm(s_all)) @ W_i2 + b_i2
__global__ __launch_bounds__(256) void kA(
    const float* __restrict__ s_heavy, const int* __restrict__ is_h,
    const float* __restrict__ h_emb, const float* __restrict__ norm1_w,
    const float* __restrict__ W_i1, const float* __restrict__ b_i1,
    const float* __restrict__ W_i2, const float* __restrict__ b_i2,
    float* __restrict__ s_all, float* __restrict__ x)
{
    const int bi = blockIdx.x;
    const int b = bi >> 8, i = bi & 255;
    const int t = threadIdx.x;
    __shared__ float y[128];
    __shared__ float o[256];
    __shared__ float h[128];
    __shared__ float red[4];

    float s = 0.f;
    if (t < 128) {
        if (is_h[bi] != 0) s = h_emb[t];
        else if (i < 192) s = s_heavy[(b * 192 + i) * 128 + t];
        s_all[bi * 128 + t] = s;
    }
    float ss = s * s;
    #pragma unroll
    for (int off = 32; off > 0; off >>= 1) ss += __shfl_xor(ss, off, 64);
    if ((t & 63) == 0) red[t >> 6] = ss;
    __syncthreads();
    float v = (red[0] + red[1] + red[2] + red[3]) * (1.0f / 128.0f);
    float inv = rsqrtf(v + 1e-6f);
    if (t < 128) y[t] = s * inv * (1.0f + norm1_w[t]);
    __syncthreads();

    float acc = b_i1[t];
    #pragma unroll 8
    for (int k = 0; k < 128; ++k) acc += y[k] * W_i1[k * 256 + t];
    o[t] = acc;
    __syncthreads();
    if (t < 128) {
        float a = o[t], g = o[t + 128];
        h[t] = a * sigm(a) * sigm(g);
    }
    __syncthreads();
    for (int c = t; c < 384; c += 256) {
        float a2 = b_i2[c];
        #pragma unroll 8
        for (int k = 0; k < 128; ++k) a2 += h[k] * W_i2[k * 384 + c];
        x[(long)bi * 384 + c] = a2;
    }
}

// Kernel X2: build frag-contiguous B panel.
// Bg uint4 per (b, kt, g, col): the 8 bf16 (j = kt*32+g*8 .. +7) a lane's MFMA B-frag needs.
__global__ __launch_bounds__(640) void kX2(
    const float* __restrict__ x, const float* __restrict__ v_all,
    unsigned* __restrict__ Bg)
{
    int blk = blockIdx.x;
    const int g = blk & 3; blk >>= 2;
    const int kt = blk & 7; const int b = blk >> 3;
    const int col = threadIdx.x;
    const int j0 = kt * 32 + g * 8;
    const float* xb = x + (long)b * 98304;
    const float* vb = v_all + (long)b * 98304;

    float vals[8];
    if (col < 256) {
        #pragma unroll
        for (int jj = 0; jj < 8; ++jj) vals[jj] = xb[(j0 + jj) * 384 + col];
    } else {
        const int cg = col - 256, r3 = cg >> 7, c3 = cg & 127;
        #pragma unroll
        for (int jj = 0; jj < 8; ++jj) {
            const int j = j0 + jj;
            vals[jj] = vb[j * 384 + r3 * 128 + c3] * xb[j * 384 + 256 + c3];
        }
    }
    uint4 outv = make_uint4(pack2bf(vals[0], vals[1]), pack2bf(vals[2], vals[3]),
                            pack2bf(vals[4], vals[5]), pack2bf(vals[6], vals[7]));
    *(uint4*)&Bg[(((long)(b * 8 + kt) * 4 + g) * 640 + col) * 4] = outv;
}

// Kernel BC (fused kB2f + kC3): per (b,i):
//  Phase B: A (96x256 bf16, LDS) @ Bg (frag-layout) via MFMA; Wf-contraction -> q_s, mu_s (LDS).
//  Phase C: mixing on the in-LDS q/mu -> q_out, mu_out.  512 thr = 8 waves.
__global__ __launch_bounds__(512, 4) void kBC(
    const float* __restrict__ rbf, const float* __restrict__ dir_ij,
    const float* __restrict__ mask_ij, const float* __restrict__ v_all,
    const float* __restrict__ W_filter, const float* __restrict__ b_filter,
    const float* __restrict__ s_all, const unsigned* __restrict__ Bg,
    const float* __restrict__ W_mu, const float* __restrict__ norm2_w,
    const float* __restrict__ W_m1, const float* __restrict__ b_m1,
    const float* __restrict__ W_m2, const float* __restrict__ b_m2,
    float* __restrict__ q_out, float* __restrict__ mu_out)
{
    const int bi = blockIdx.x, b = bi >> 8, i = bi & 255;
    const int t = threadIdx.x;
    const int lane = t & 63, w = t >> 6, g = lane >> 4, l16 = lane & 15;

    __shared__ unsigned A_lds[96 * 132];   // 96 rows x 264 bf16 (k-pairs, pad)
    __shared__ float rbf_s[5120];          // phase B: rbf; phase C: aliased temps
    __shared__ float dir_s[768];
    __shared__ float m_s[256];
    __shared__ float dmuR_s[384];
    __shared__ float dmumu_s[384];
    __shared__ float q_s[128];
    __shared__ float mu_s[384];

    for (int i2 = t; i2 < 5120; i2 += 512) rbf_s[i2] = rbf[(long)bi * 5120 + i2];
    for (int i2 = t; i2 < 768; i2 += 512) dir_s[i2] = dir_ij[(long)bi * 768 + i2];
    for (int i2 = t; i2 < 256; i2 += 512) m_s[i2] = mask_ij[(long)bi * 256 + i2];
    __syncthreads();

    // ---- build A (bf16 pairs) ----
    for (int e = t; e < 96 * 128; e += 512) {
        int row = e >> 7, j2 = e & 127;
        float v01[2];
        #pragma unroll
        for (int u = 0; u < 2; ++u) {
            int j = 2 * j2 + u;
            float val = 0.f;
            if (row < 20) val = rbf_s[j * 20 + row] * m_s[j];
            else if (row == 20) val = m_s[j];
            else if (row >= 32) {
                int idx = row - 32;
                if (idx < 63) {
                    int r3 = (idx >= 42) ? 2 : ((idx >= 21) ? 1 : 0);
                    int r = idx - 21 * r3;
                    float base = (r < 20) ? rbf_s[j * 20 + r] : 1.f;
                    val = base * m_s[j] * dir_s[j * 3 + r3];
                }
            }
            v01[u] = val;
        }
        A_lds[row * 132 + j2] = pack2bf(v01[0], v01[1]);
    }
    __syncthreads();

    // ---- tile assignment ----
    int colR[4];
    #pragma unroll
    for (int ci = 0; ci < 4; ++ci) {
        int ct = (w < 2) ? (4 * w + ci) : (4 * w + 8 + ci);
        colR[ci] = ct * 16 + l16;
    }
    const int col2 = (8 + w) * 16 + l16;

    const unsigned* BgB = Bg + (long)b * 81920;

    f32x4 accR[4][2];
    f32x4 acc2[4];
    #pragma unroll
    for (int ci = 0; ci < 4; ++ci) {
        #pragma unroll
        for (int rt = 0; rt < 2; ++rt) accR[ci][rt] = {0.f, 0.f, 0.f, 0.f};
        acc2[ci] = {0.f, 0.f, 0.f, 0.f};
    }

    // ---- GEMM: K = 256 j = 8 k-steps of 32 ----
    #pragma unroll 2
    for (int kt = 0; kt < 8; ++kt) {
        bf16x8 af[6];
        #pragma unroll
        for (int rt = 0; rt < 6; ++rt)
            af[rt] = *(const bf16x8*)&A_lds[(rt * 16 + l16) * 132 + kt * 16 + g * 4];
        const unsigned* Bk = BgB + ((long)kt * 4 + g) * 640 * 4;
        bf16x8 bfr[5];
        #pragma unroll
        for (int u = 0; u < 4; ++u)
            bfr[u] = *(const bf16x8*)&Bk[colR[u] * 4];
        bfr[4] = *(const bf16x8*)&Bk[col2 * 4];
        #pragma unroll
        for (int ci = 0; ci < 4; ++ci) {
            accR[ci][0] = __builtin_amdgcn_mfma_f32_16x16x32_bf16(af[0], bfr[ci], accR[ci][0], 0, 0, 0);
            accR[ci][1] = __builtin_amdgcn_mfma_f32_16x16x32_bf16(af[1], bfr[ci], accR[ci][1], 0, 0, 0);
        }
        #pragma unroll
        for (int rt = 0; rt < 4; ++rt)
            acc2[rt] = __builtin_amdgcn_mfma_f32_16x16x32_bf16(af[2 + rt], bfr[4], acc2[rt], 0, 0, 0);
    }

    // ---- epilogue T2 -> dmuR_s ----
    {
        float p3[3] = {0.f, 0.f, 0.f};
        const int c = 128 + 16 * w + l16;
        #pragma unroll
        for (int rt = 0; rt < 4; ++rt) {
            #pragma unroll
            for (int e = 0; e < 4; ++e) {
                int l = rt * 16 + g * 4 + e;
                if (l < 63) {
                    int r3 = (l >= 42) ? 2 : ((l >= 21) ? 1 : 0);
                    int rr = l - 21 * r3;
                    float wgt = (rr < 20) ? W_filter[rr * 384 + c] : b_filter[c];
                    p3[r3] += wgt * acc2[rt][e];
                }
            }
        }
        #pragma unroll
        for (int r3 = 0; r3 < 3; ++r3) {
            float a = p3[r3];
            a += __shfl_xor(a, 16, 64);
            a += __shfl_xor(a, 32, 64);
            if (lane < 16) dmuR_s[r3 * 128 + 16 * w + l16] = a;
        }
    }

    // ---- epilogue T1/T3 -> q_s / dmumu_s ----
    #pragma unroll
    for (int ci = 0; ci < 4; ++ci) {
        const int cwf = (w < 2) ? colR[ci] : (256 + ((colR[ci] - 256) & 127));
        float p = 0.f;
        #pragma unroll
        for (int rt = 0; rt < 2; ++rt) {
            #pragma unroll
            for (int e = 0; e < 4; ++e) {
                int row = rt * 16 + g * 4 + e;
                if (row <= 20) {
                    float wgt = (row < 20) ? W_filter[row * 384 + cwf] : b_filter[cwf];
                    p += wgt * accR[ci][rt][e];
                }
            }
        }
        p += __shfl_xor(p, 16, 64);
        p += __shfl_xor(p, 32, 64);
        if (lane < 16) {
            if (w < 2) {
                int c = colR[ci];
                q_s[c] = s_all[bi * 128 + c] + p;
            } else {
                dmumu_s[colR[ci] - 256] = p;
            }
        }
    }
    __syncthreads();
    for (int e2 = t; e2 < 384; e2 += 512)
        mu_s[e2] = v_all[(long)bi * 384 + e2] + dmuR_s[e2] + dmumu_s[e2];
    __syncthreads();

    // ================= Phase C: mixing (kC3 body, temps aliased on rbf_s) =================
    float* part   = rbf_s;           // [2][768]
    float* muV    = rbf_s + 1536;    // 384
    float* muW    = rbf_s + 1920;    // 384
    float* ctx    = rbf_s + 2304;    // 256
    float* o_part = rbf_s + 2560;    // [2][256]
    float* hsm    = rbf_s + 3072;    // 128
    float* x2s    = rbf_s + 3200;    // 384
    float* red    = rbf_s + 3584;    // 8

    const int c = t & 255, kh = t >> 8;
    float qv = (t < 128) ? q_s[t] : 0.f;

    // mu_mix (split-K halves)
    {
        float m0 = 0.f, m1 = 0.f, m2 = 0.f;
        const int k0 = kh * 64;
        #pragma unroll 8
        for (int k = k0; k < k0 + 64; ++k) {
            float ww = W_mu[k * 256 + c];
            m0 += mu_s[k] * ww;
            m1 += mu_s[128 + k] * ww;
            m2 += mu_s[256 + k] * ww;
        }
        part[kh * 768 + c] = m0; part[kh * 768 + 256 + c] = m1; part[kh * 768 + 512 + c] = m2;
    }
    float ss = qv * qv;
    #pragma unroll
    for (int off = 32; off > 0; off >>= 1) ss += __shfl_xor(ss, off, 64);
    if ((t & 63) == 0) red[t >> 6] = ss;
    __syncthreads();
    for (int idx = t; idx < 768; idx += 512) {
        const int r3 = idx >> 8, cc = idx & 255;
        float val = part[idx] + part[768 + idx];
        if (cc < 128) muV[r3 * 128 + cc] = val;
        else          muW[r3 * 128 + (cc - 128)] = val;
    }
    __syncthreads();
    float mean = (red[0] + red[1] + red[2] + red[3] + red[4] + red[5] + red[6] + red[7])
                 * (1.0f / 128.0f);
    if (t < 128) {
        ctx[t] = qv * rsqrtf(mean + 1e-6f) * (1.0f + norm2_w[t]);
    } else if (t < 256) {
        int d2 = t - 128;
        ctx[t] = sqrtf(muV[d2] * muV[d2] + muV[128 + d2] * muV[128 + d2]
                       + muV[256 + d2] * muV[256 + d2] + 1e-6f);
    }
    __syncthreads();

    // o = ctx @ W_m1 (split-K halves)
    {
        float acc = 0.f;
        const int k0 = kh * 128;
        #pragma unroll 8
        for (int k = k0; k < k0 + 128; ++k) acc += ctx[k] * W_m1[k * 256 + c];
        o_part[kh * 256 + c] = acc;
    }
    __syncthreads();
    if (t < 128) {
        float a  = o_part[t]       + o_part[256 + t]       + b_m1[t];
        float gg = o_part[t + 128] + o_part[256 + t + 128] + b_m1[t + 128];
        hsm[t] = a * sigm(a) * sigm(gg);
    }
    __syncthreads();
    if (t < 384) {
        float a2 = b_m2[t];
        #pragma unroll 8
        for (int k = 0; k < 128; ++k) a2 += hsm[k] * W_m2[k * 384 + t];
        x2s[t] = a2;
    }
    __syncthreads();

    if (t < 128) {
        const int d = t;
        float vw = muV[d] * muW[d] + muV[128 + d] * muW[128 + d] + muV[256 + d] * muW[256 + d];
        if (i < 192)
            q_out[((long)b * 192 + i) * 128 + d] = qv + x2s[d] + x2s[256 + d] * vw;
        #pragma unroll
        for (int r = 0; r < 3; ++r)
            mu_out[((long)bi * 3 + r) * 128 + d] =
                mu_s[r * 128 + d] + x2s[128 + d] * muW[r * 128 + d];
    }
}

extern "C" void kernel_launch(void* const* d_in, const int* in_sizes, int n_in,
                              void* d_out, int out_size, void* d_ws, size_t ws_size,
                              hipStream_t stream) {
    (void)in_sizes; (void)n_in; (void)out_size;
    const float* s_heavy  = (const float*)d_in[0];
    const float* v_all    = (const float*)d_in[1];
    const float* rbf      = (const float*)d_in[2];
    const float* dir_ij   = (const float*)d_in[3];
    const float* mask_ij  = (const float*)d_in[4];
    const int*   is_h     = (const int*)d_in[5];
    const float* h_emb    = (const float*)d_in[6];
    const float* W_filter = (const float*)d_in[7];
    const float* b_filter = (const float*)d_in[8];
    const float* norm1_w  = (const float*)d_in[9];
    const float* W_i1     = (const float*)d_in[10];
    const float* b_i1     = (const float*)d_in[11];
    const float* W_i2     = (const float*)d_in[12];
    const float* b_i2     = (const float*)d_in[13];
    const float* norm2_w  = (const float*)d_in[14];
    const float* W_m1     = (const float*)d_in[15];
    const float* b_m1     = (const float*)d_in[16];
    const float* W_m2     = (const float*)d_in[17];
    const float* b_m2     = (const float*)d_in[18];
    const float* W_mu     = (const float*)d_in[19];

    // ws layout (f32 units): s_all 0 | x 65536 | Bg(u32) 262144
    const size_t need = (size_t)(262144 + 163840) * 4;
    if (ws_size < need) return;
    float* ws    = (float*)d_ws;
    float* s_all = ws;
    float* x     = ws + 65536;
    unsigned* Bg = (unsigned*)(ws + 262144);   // 2*8*4*640*4 u32 = 163840

    float* q_out  = (float*)d_out;               // (2,192,128)
    float* mu_out = q_out + 2 * 192 * 128;       // (2,256,3,128)

    kA<<<512, 256, 0, stream>>>(s_heavy, is_h, h_emb, norm1_w, W_i1, b_i1, W_i2, b_i2,
                                s_all, x);
    kX2<<<64, 640, 0, stream>>>(x, v_all, Bg);
    kBC<<<512, 512, 0, stream>>>(rbf, dir_ij, mask_ij, v_all, W_filter, b_filter,
                                 s_all, Bg, W_mu, norm2_w, W_m1, b_m1, W_m2, b_m2,
                                 q_out, mu_out);
}

// Round 11
// 58.572 us; speedup vs baseline: 3.7884x; 1.0879x over previous
//
#include <hip/hip_runtime.h>
#include <hip/hip_bf16.h>

#define DEV static __device__ __forceinline__

typedef __attribute__((ext_vector_type(8))) short bf16x8;
typedef __attribute__((ext_vector_type(4))) float f32x4;

DEV float sigm(float x) { return 1.0f / (1.0f + __expf(-x)); }

DEV unsigned pack2bf(float a, float b) {
    unsigned ua = __float_as_uint(a); ua = (ua + 0x7FFF + ((ua >> 16) & 1)) >> 16;
    unsigned ub = __float_as_uint(b); ub = (ub + 0x7FFF + ((ub >> 16) & 1)) >> 16;
    return ua | (ub << 16);
}
DEV unsigned short f2bf(float a) {
    unsigned ua = __float_as_uint(a);
    return (unsigned short)((ua + 0x7FFF + ((ua >> 16) & 1)) >> 16);
}
DEV float bfu2f(unsigned short u) { return __uint_as_float(((unsigned)u) << 16); }
DEV float lo2f(unsigned u) { return __uint_as_float(u << 16); }
DEV float hi2f(unsigned u) { return __uint_as_float(u & 0xffff0000u); }

// B=2, N=256, Nh=192, D=128, R=20

// Kernel A: blocks <512: per-atom s_all + x. blocks 512..575: pack mixing weights to bf16.
__global__ __launch_bounds__(256) void kA(
    const float* __restrict__ s_heavy, const int* __restrict__ is_h,
    const float* __restrict__ h_emb, const float* __restrict__ norm1_w,
    const float* __restrict__ W_i1, const float* __restrict__ b_i1,
    const float* __restrict__ W_i2, const float* __restrict__ b_i2,
    const float* __restrict__ W_mu, const float* __restrict__ W_m1,
    const float* __restrict__ W_m2, const float* __restrict__ W_filter,
    const float* __restrict__ b_filter,
    float* __restrict__ s_all, float* __restrict__ x,
    unsigned* __restrict__ Wmu_p, unsigned* __restrict__ Wm1_p,
    unsigned* __restrict__ Wm2_p, unsigned* __restrict__ Wfb_p)
{
    const int blk = blockIdx.x;
    const int t = threadIdx.x;
    if (blk >= 512) {
        const int idx0 = (blk - 512) * 256 + t;       // 0..16383
        {   // W_mu pairs: 64 k2 x 256 c
            int k2 = idx0 >> 8, c = idx0 & 255;
            Wmu_p[idx0] = pack2bf(W_mu[(2 * k2) * 256 + c], W_mu[(2 * k2 + 1) * 256 + c]);
        }
        #pragma unroll
        for (int r = 0; r < 2; ++r) {                 // W_m1 pairs: 128 k2 x 256 c
            int s = idx0 + r * 16384;
            int k2 = s >> 8, c = s & 255;
            Wm1_p[s] = pack2bf(W_m1[(2 * k2) * 256 + c], W_m1[(2 * k2 + 1) * 256 + c]);
        }
        for (int s = idx0; s < 24576; s += 16384) {   // W_m2 pairs: 64 k2 x 384 c
            int k2 = s / 384, c = s - k2 * 384;
            Wm2_p[s] = pack2bf(W_m2[(2 * k2) * 384 + c], W_m2[(2 * k2 + 1) * 384 + c]);
        }
        for (int s = idx0; s < 4032; s += 16384) {    // [W_filter(7680) | b_filter(384)] u16
            int e = 2 * s;
            float v0 = (e < 7680) ? W_filter[e] : b_filter[e - 7680];
            float v1 = (e + 1 < 7680) ? W_filter[e + 1] : b_filter[e + 1 - 7680];
            Wfb_p[s] = pack2bf(v0, v1);
        }
        return;
    }
    const int bi = blk;
    const int b = bi >> 8, i = bi & 255;
    __shared__ float y[128];
    __shared__ float o[256];
    __shared__ float h[128];
    __shared__ float red[4];

    float s = 0.f;
    if (t < 128) {
        if (is_h[bi] != 0) s = h_emb[t];
        else if (i < 192) s = s_heavy[(b * 192 + i) * 128 + t];
        s_all[bi * 128 + t] = s;
    }
    float ss = s * s;
    #pragma unroll
    for (int off = 32; off > 0; off >>= 1) ss += __shfl_xor(ss, off, 64);
    if ((t & 63) == 0) red[t >> 6] = ss;
    __syncthreads();
    float v = (red[0] + red[1] + red[2] + red[3]) * (1.0f / 128.0f);
    float inv = rsqrtf(v + 1e-6f);
    if (t < 128) y[t] = s * inv * (1.0f + norm1_w[t]);
    __syncthreads();

    float acc = b_i1[t];
    #pragma unroll 8
    for (int k = 0; k < 128; ++k) acc += y[k] * W_i1[k * 256 + t];
    o[t] = acc;
    __syncthreads();
    if (t < 128) {
        float a = o[t], g = o[t + 128];
        h[t] = a * sigm(a) * sigm(g);
    }
    __syncthreads();
    for (int c = t; c < 384; c += 256) {
        float a2 = b_i2[c];
        #pragma unroll 8
        for (int k = 0; k < 128; ++k) a2 += h[k] * W_i2[k * 384 + c];
        x[(long)bi * 384 + c] = a2;
    }
}

// Kernel X2: build frag-contiguous B panel (uint4 per (b,kt,g,col) = 8 bf16 along j).
__global__ __launch_bounds__(640) void kX2(
    const float* __restrict__ x, const float* __restrict__ v_all,
    unsigned* __restrict__ Bg)
{
    int blk = blockIdx.x;
    const int g = blk & 3; blk >>= 2;
    const int kt = blk & 7; const int b = blk >> 3;
    const int col = threadIdx.x;
    const int j0 = kt * 32 + g * 8;
    const float* xb = x + (long)b * 98304;
    const float* vb = v_all + (long)b * 98304;

    float vals[8];
    if (col < 256) {
        #pragma unroll
        for (int jj = 0; jj < 8; ++jj) vals[jj] = xb[(j0 + jj) * 384 + col];
    } else {
        const int cg = col - 256, r3 = cg >> 7, c3 = cg & 127;
        #pragma unroll
        for (int jj = 0; jj < 8; ++jj) {
            const int j = j0 + jj;
            vals[jj] = vb[j * 384 + r3 * 128 + c3] * xb[j * 384 + 256 + c3];
        }
    }
    uint4 outv = make_uint4(pack2bf(vals[0], vals[1]), pack2bf(vals[2], vals[3]),
                            pack2bf(vals[4], vals[5]), pack2bf(vals[6], vals[7]));
    *(uint4*)&Bg[(((long)(b * 8 + kt) * 4 + g) * 640 + col) * 4] = outv;
}

// Kernel BC (fused B+C): per (b,i):
//  Phase B: A (96x256 bf16 in LDS) @ Bg via MFMA; Wf contraction -> q_s, mu_s (LDS).
//  Phase C: mixing with bf16-packed weights -> q_out, mu_out.  512 thr = 8 waves.
__global__ __launch_bounds__(512, 4) void kBC(
    const float* __restrict__ rbf, const float* __restrict__ dir_ij,
    const float* __restrict__ mask_ij, const float* __restrict__ v_all,
    const float* __restrict__ s_all, const unsigned* __restrict__ Bg,
    const unsigned* __restrict__ Wmu_p, const float* __restrict__ norm2_w,
    const unsigned* __restrict__ Wm1_p, const float* __restrict__ b_m1,
    const unsigned* __restrict__ Wm2_p, const float* __restrict__ b_m2,
    const unsigned* __restrict__ Wfb_p,
    float* __restrict__ q_out, float* __restrict__ mu_out)
{
    const int bi = blockIdx.x, b = bi >> 8, i = bi & 255;
    const int t = threadIdx.x;
    const int lane = t & 63, w = t >> 6, g = lane >> 4, l16 = lane & 15;

    __shared__ unsigned short A16[96 * 264];  // 96 rows x 264 bf16 (row stride 264 u16)
    __shared__ float rbf_s[5376];             // [256 j][21] padded; phase C: aliased temps
    __shared__ float dir_s[768];
    __shared__ float m_s[256];
    __shared__ float dmuR_s[384];
    __shared__ float dmumu_s[384];
    __shared__ float q_s[128];
    __shared__ float mu_s[384];

    for (int i2 = t; i2 < 5120; i2 += 512) {
        int j = i2 / 20, r = i2 - j * 20;
        rbf_s[j * 21 + r] = rbf[(long)bi * 5120 + i2];
    }
    for (int i2 = t; i2 < 768; i2 += 512) dir_s[i2] = dir_ij[(long)bi * 768 + i2];
    for (int i2 = t; i2 < 256; i2 += 512) m_s[i2] = mask_ij[(long)bi * 256 + i2];
    __syncthreads();

    // ---- build A: one (row, j) per thread; conflict-free reads (stride 21) ----
    for (int e = t; e < 96 * 256; e += 512) {
        const int row = e >> 8, j = e & 255;
        float val = 0.f;
        if (row < 20) val = rbf_s[j * 21 + row] * m_s[j];
        else if (row == 20) val = m_s[j];
        else if (row >= 32) {
            int idx = row - 32;
            if (idx < 63) {
                int r3 = (idx >= 42) ? 2 : ((idx >= 21) ? 1 : 0);
                int r = idx - 21 * r3;
                float base = (r < 20) ? rbf_s[j * 21 + r] : 1.f;
                val = base * m_s[j] * dir_s[j * 3 + r3];
            }
        }
        A16[row * 264 + j] = f2bf(val);
    }
    __syncthreads();

    // ---- tile assignment ----
    int colR[4];
    #pragma unroll
    for (int ci = 0; ci < 4; ++ci) {
        int ct = (w < 2) ? (4 * w + ci) : (4 * w + 8 + ci);
        colR[ci] = ct * 16 + l16;
    }
    const int col2 = (8 + w) * 16 + l16;

    const unsigned* BgB = Bg + (long)b * 81920;
    const unsigned short* Wfb16 = (const unsigned short*)Wfb_p;

    f32x4 accR[4][2];
    f32x4 acc2[4];
    #pragma unroll
    for (int ci = 0; ci < 4; ++ci) {
        #pragma unroll
        for (int rt = 0; rt < 2; ++rt) accR[ci][rt] = {0.f, 0.f, 0.f, 0.f};
        acc2[ci] = {0.f, 0.f, 0.f, 0.f};
    }

    // ---- GEMM: K = 256 j = 8 k-steps of 32 ----
    #pragma unroll 2
    for (int kt = 0; kt < 8; ++kt) {
        bf16x8 af[6];
        #pragma unroll
        for (int rt = 0; rt < 6; ++rt)
            af[rt] = *(const bf16x8*)&A16[(rt * 16 + l16) * 264 + kt * 32 + g * 8];
        const unsigned* Bk = BgB + ((long)kt * 4 + g) * 640 * 4;
        bf16x8 bfr[5];
        #pragma unroll
        for (int u = 0; u < 4; ++u)
            bfr[u] = *(const bf16x8*)&Bk[colR[u] * 4];
        bfr[4] = *(const bf16x8*)&Bk[col2 * 4];
        #pragma unroll
        for (int ci = 0; ci < 4; ++ci) {
            accR[ci][0] = __builtin_amdgcn_mfma_f32_16x16x32_bf16(af[0], bfr[ci], accR[ci][0], 0, 0, 0);
            accR[ci][1] = __builtin_amdgcn_mfma_f32_16x16x32_bf16(af[1], bfr[ci], accR[ci][1], 0, 0, 0);
        }
        #pragma unroll
        for (int rt = 0; rt < 4; ++rt)
            acc2[rt] = __builtin_amdgcn_mfma_f32_16x16x32_bf16(af[2 + rt], bfr[4], acc2[rt], 0, 0, 0);
    }

    // ---- epilogue T2 -> dmuR_s ----
    {
        float p3[3] = {0.f, 0.f, 0.f};
        const int c = 128 + 16 * w + l16;
        #pragma unroll
        for (int rt = 0; rt < 4; ++rt) {
            #pragma unroll
            for (int e = 0; e < 4; ++e) {
                int l = rt * 16 + g * 4 + e;
                if (l < 63) {
                    int r3 = (l >= 42) ? 2 : ((l >= 21) ? 1 : 0);
                    int rr = l - 21 * r3;
                    float wgt = bfu2f((rr < 20) ? Wfb16[rr * 384 + c] : Wfb16[7680 + c]);
                    p3[r3] += wgt * acc2[rt][e];
                }
            }
        }
        #pragma unroll
        for (int r3 = 0; r3 < 3; ++r3) {
            float a = p3[r3];
            a += __shfl_xor(a, 16, 64);
            a += __shfl_xor(a, 32, 64);
            if (lane < 16) dmuR_s[r3 * 128 + 16 * w + l16] = a;
        }
    }

    // ---- epilogue T1/T3 -> q_s / dmumu_s ----
    #pragma unroll
    for (int ci = 0; ci < 4; ++ci) {
        const int cwf = (w < 2) ? colR[ci] : (256 + ((colR[ci] - 256) & 127));
        float p = 0.f;
        #pragma unroll
        for (int rt = 0; rt < 2; ++rt) {
            #pragma unroll
            for (int e = 0; e < 4; ++e) {
                int row = rt * 16 + g * 4 + e;
                if (row <= 20) {
                    float wgt = bfu2f((row < 20) ? Wfb16[row * 384 + cwf] : Wfb16[7680 + cwf]);
                    p += wgt * accR[ci][rt][e];
                }
            }
        }
        p += __shfl_xor(p, 16, 64);
        p += __shfl_xor(p, 32, 64);
        if (lane < 16) {
            if (w < 2) {
                int c = colR[ci];
                q_s[c] = s_all[bi * 128 + c] + p;
            } else {
                dmumu_s[colR[ci] - 256] = p;
            }
        }
    }
    __syncthreads();
    for (int e2 = t; e2 < 384; e2 += 512)
        mu_s[e2] = v_all[(long)bi * 384 + e2] + dmuR_s[e2] + dmumu_s[e2];
    __syncthreads();

    // ================= Phase C: mixing (bf16-packed weights; temps alias rbf_s) ==========
    float* part   = rbf_s;           // [2][768]
    float* muV    = rbf_s + 1536;    // 384
    float* muW    = rbf_s + 1920;    // 384
    float* ctx    = rbf_s + 2304;    // 256
    float* o_part = rbf_s + 2560;    // [2][256]
    float* hsm    = rbf_s + 3072;    // 128
    float* x2s    = rbf_s + 3200;    // 384
    float* red    = rbf_s + 3584;    // 8

    const int c = t & 255, kh = t >> 8;
    float qv = (t < 128) ? q_s[t] : 0.f;

    // mu_mix (split-K halves, packed pairs along k)
    {
        float m0 = 0.f, m1 = 0.f, m2 = 0.f;
        const int k20 = kh * 32;
        #pragma unroll 8
        for (int k2 = k20; k2 < k20 + 32; ++k2) {
            unsigned u = Wmu_p[k2 * 256 + c];
            float w0 = lo2f(u), w1 = hi2f(u);
            m0 += mu_s[2 * k2] * w0 + mu_s[2 * k2 + 1] * w1;
            m1 += mu_s[128 + 2 * k2] * w0 + mu_s[128 + 2 * k2 + 1] * w1;
            m2 += mu_s[256 + 2 * k2] * w0 + mu_s[256 + 2 * k2 + 1] * w1;
        }
        part[kh * 768 + c] = m0; part[kh * 768 + 256 + c] = m1; part[kh * 768 + 512 + c] = m2;
    }
    float ss = qv * qv;
    #pragma unroll
    for (int off = 32; off > 0; off >>= 1) ss += __shfl_xor(ss, off, 64);
    if ((t & 63) == 0) red[t >> 6] = ss;
    __syncthreads();
    for (int idx = t; idx < 768; idx += 512) {
        const int r3 = idx >> 8, cc = idx & 255;
        float val = part[idx] + part[768 + idx];
        if (cc < 128) muV[r3 * 128 + cc] = val;
        else          muW[r3 * 128 + (cc - 128)] = val;
    }
    __syncthreads();
    float mean = (red[0] + red[1] + red[2] + red[3] + red[4] + red[5] + red[6] + red[7])
                 * (1.0f / 128.0f);
    if (t < 128) {
        ctx[t] = qv * rsqrtf(mean + 1e-6f) * (1.0f + norm2_w[t]);
    } else if (t < 256) {
        int d2 = t - 128;
        ctx[t] = sqrtf(muV[d2] * muV[d2] + muV[128 + d2] * muV[128 + d2]
                       + muV[256 + d2] * muV[256 + d2] + 1e-6f);
    }
    __syncthreads();

    // o = ctx @ W_m1 (split-K halves, packed)
    {
        float acc = 0.f;
        const int k20 = kh * 64;
        #pragma unroll 8
        for (int k2 = k20; k2 < k20 + 64; ++k2) {
            unsigned u = Wm1_p[k2 * 256 + c];
            acc += ctx[2 * k2] * lo2f(u) + ctx[2 * k2 + 1] * hi2f(u);
        }
        o_part[kh * 256 + c] = acc;
    }
    __syncthreads();
    if (t < 128) {
        float a  = o_part[t]       + o_part[256 + t]       + b_m1[t];
        float gg = o_part[t + 128] + o_part[256 + t + 128] + b_m1[t + 128];
        hsm[t] = a * sigm(a) * sigm(gg);
    }
    __syncthreads();
    if (t < 384) {
        float a2 = b_m2[t];
        #pragma unroll 8
        for (int k2 = 0; k2 < 64; ++k2) {
            unsigned u = Wm2_p[k2 * 384 + t];
            a2 += hsm[2 * k2] * lo2f(u) + hsm[2 * k2 + 1] * hi2f(u);
        }
        x2s[t] = a2;
    }
    __syncthreads();

    if (t < 128) {
        const int d = t;
        float vw = muV[d] * muW[d] + muV[128 + d] * muW[128 + d] + muV[256 + d] * muW[256 + d];
        if (i < 192)
            q_out[((long)b * 192 + i) * 128 + d] = qv + x2s[d] + x2s[256 + d] * vw;
        #pragma unroll
        for (int r = 0; r < 3; ++r)
            mu_out[((long)bi * 3 + r) * 128 + d] =
                mu_s[r * 128 + d] + x2s[128 + d] * muW[r * 128 + d];
    }
}

extern "C" void kernel_launch(void* const* d_in, const int* in_sizes, int n_in,
                              void* d_out, int out_size, void* d_ws, size_t ws_size,
                              hipStream_t stream) {
    (void)in_sizes; (void)n_in; (void)out_size;
    const float* s_heavy  = (const float*)d_in[0];
    const float* v_all    = (const float*)d_in[1];
    const float* rbf      = (const float*)d_in[2];
    const float* dir_ij   = (const float*)d_in[3];
    const float* mask_ij  = (const float*)d_in[4];
    const int*   is_h     = (const int*)d_in[5];
    const float* h_emb    = (const float*)d_in[6];
    const float* W_filter = (const float*)d_in[7];
    const float* b_filter = (const float*)d_in[8];
    const float* norm1_w  = (const float*)d_in[9];
    const float* W_i1     = (const float*)d_in[10];
    const float* b_i1     = (const float*)d_in[11];
    const float* W_i2     = (const float*)d_in[12];
    const float* b_i2     = (const float*)d_in[13];
    const float* norm2_w  = (const float*)d_in[14];
    const float* W_m1     = (const float*)d_in[15];
    const float* b_m1     = (const float*)d_in[16];
    const float* W_m2     = (const float*)d_in[17];
    const float* b_m2     = (const float*)d_in[18];
    const float* W_mu     = (const float*)d_in[19];

    // ws layout (f32 units): s_all 0 | x 65536 | Bg 262144(+163840) | Wmu_p 425984(+16384)
    //  | Wm1_p 442368(+32768) | Wm2_p 475136(+24576) | Wfb_p 499712(+4032)
    const size_t need = (size_t)503744 * 4;
    if (ws_size < need) return;
    float* ws    = (float*)d_ws;
    float* s_all = ws;
    float* x     = ws + 65536;
    unsigned* Bg    = (unsigned*)(ws + 262144);
    unsigned* Wmu_p = (unsigned*)(ws + 425984);
    unsigned* Wm1_p = (unsigned*)(ws + 442368);
    unsigned* Wm2_p = (unsigned*)(ws + 475136);
    unsigned* Wfb_p = (unsigned*)(ws + 499712);

    float* q_out  = (float*)d_out;               // (2,192,128)
    float* mu_out = q_out + 2 * 192 * 128;       // (2,256,3,128)

    kA<<<576, 256, 0, stream>>>(s_heavy, is_h, h_emb, norm1_w, W_i1, b_i1, W_i2, b_i2,
                                W_mu, W_m1, W_m2, W_filter, b_filter,
                                s_all, x, Wmu_p, Wm1_p, Wm2_p, Wfb_p);
    kX2<<<64, 640, 0, stream>>>(x, v_all, Bg);
    kBC<<<512, 512, 0, stream>>>(rbf, dir_ij, mask_ij, v_all, s_all, Bg,
                                 Wmu_p, norm2_w, Wm1_p, b_m1, Wm2_p, b_m2, Wfb_p,
                                 q_out, mu_out);
}